// Round 1
// baseline (6166.441 us; speedup 1.0000x reference)
//
#include <hip/hip_runtime.h>

#define DM 128
#define NH 8
#define DH 16

typedef __bf16 bf8 __attribute__((ext_vector_type(8)));
typedef float  f4  __attribute__((ext_vector_type(4)));

__device__ __forceinline__ f4 mfma16(bf8 a, bf8 b, f4 c){
  return __builtin_amdgcn_mfma_f32_16x16x32_bf16(a, b, c, 0, 0, 0);
}

// convert 8 contiguous fp32 -> bf16x8 fragment
__device__ __forceinline__ bf8 cvt8(const float* __restrict__ p){
  f4 u = *(const f4*)p;
  f4 v = *(const f4*)(p + 4);
  bf8 r;
  r[0]=(__bf16)u[0]; r[1]=(__bf16)u[1]; r[2]=(__bf16)u[2]; r[3]=(__bf16)u[3];
  r[4]=(__bf16)v[0]; r[5]=(__bf16)v[1]; r[6]=(__bf16)v[2]; r[7]=(__bf16)v[3];
  return r;
}

// B fragment from pre-transposed bf16 weight WT[out][k]; ptr must be at (col0,k0)
__device__ __forceinline__ bf8 bfragT(const __bf16* __restrict__ WT, int ldk, int lane){
  const __bf16* p = WT + (size_t)(lane & 15) * ldk + ((lane >> 4) << 3);
  return *(const bf8*)p;
}

// ---------------- weight prep: W[K][M] (fp32) -> WT[M][K] (bf16) ----------------
__global__ void k_transpose(const float* __restrict__ W, __bf16* __restrict__ WT, int K, int M){
  int idx = blockIdx.x * 256 + threadIdx.x;
  if (idx >= K * M) return;
  int m = idx / K, k = idx - m * K;
  WT[idx] = (__bf16)W[(size_t)k * M + m];
}

// ---------------- K1: Q,K,V = h @ Wq/Wk/Wv ----------------
__global__ __launch_bounds__(256) void k_qkv(const float* __restrict__ h,
    const __bf16* __restrict__ WqT, const __bf16* __restrict__ WkT, const __bf16* __restrict__ WvT,
    float* __restrict__ Q, float* __restrict__ K, float* __restrict__ V, int N)
{
  int lane = threadIdx.x & 63;
  int r0 = (blockIdx.x * 4 + (threadIdx.x >> 6)) * 16;
  if (r0 + 16 > N) return;
  bf8 a[4];
  int arow = r0 + (lane & 15);
  int koff = (lane >> 4) << 3;
#pragma unroll
  for (int kt = 0; kt < 4; ++kt)
    a[kt] = cvt8(h + (size_t)arow * DM + kt * 32 + koff);

  const __bf16* Ws[3] = {WqT, WkT, WvT};
  float* Os[3] = {Q, K, V};
  int crow = r0 + ((lane >> 4) << 2);
  int ccol = lane & 15;
#pragma unroll
  for (int o = 0; o < 3; ++o){
#pragma unroll
    for (int nt = 0; nt < 8; ++nt){
      f4 acc = {0.f, 0.f, 0.f, 0.f};
#pragma unroll
      for (int kt = 0; kt < 4; ++kt)
        acc = mfma16(a[kt], bfragT(Ws[o] + (size_t)(nt * 16) * DM + kt * 32, DM, lane), acc);
      float* outp = Os[o] + (size_t)crow * DM + nt * 16 + ccol;
      outp[0] = acc[0]; outp[DM] = acc[1]; outp[2 * DM] = acc[2]; outp[3 * DM] = acc[3];
    }
  }
}

// ---------------- K2: fused Eh GEMM + edge scoring + atomic scatter ----------------
__global__ __launch_bounds__(256) void k_edge(const float* __restrict__ e,
    const __bf16* __restrict__ WeT,
    const float* __restrict__ Qf, const float* __restrict__ Kf, const float* __restrict__ Vf,
    const int* __restrict__ src, const int* __restrict__ dst,
    float* __restrict__ wV, float* __restrict__ zf, int E)
{
  __shared__ float Eh[64][132];     // +4 pad: breaks 32-way bank conflict on head-slice reads
  __shared__ int s_src[64], s_dst[64];
  int tid = threadIdx.x, lane = tid & 63, wave = tid >> 6;
  int e0 = blockIdx.x * 64;
  if (tid < 64){
    int ei = e0 + tid;
    bool v = ei < E;
    s_src[tid] = v ? src[ei] : 0;
    s_dst[tid] = v ? dst[ei] : 0;
  }
  // phase 1: Eh tile = e[e0:e0+64] @ We  (each wave does 16 rows)
  int er = e0 + wave * 16 + (lane & 15);
  if (er >= E) er = E - 1;
  int koff = (lane >> 4) << 3;
  bf8 a[4];
#pragma unroll
  for (int kt = 0; kt < 4; ++kt)
    a[kt] = cvt8(e + (size_t)er * DM + kt * 32 + koff);
  int lrow = wave * 16 + ((lane >> 4) << 2);
  int ccol = lane & 15;
#pragma unroll
  for (int nt = 0; nt < 8; ++nt){
    f4 acc = {0.f, 0.f, 0.f, 0.f};
#pragma unroll
    for (int kt = 0; kt < 4; ++kt)
      acc = mfma16(a[kt], bfragT(WeT + (size_t)(nt * 16) * DM + kt * 32, DM, lane), acc);
    int col = nt * 16 + ccol;
#pragma unroll
    for (int r = 0; r < 4; ++r) Eh[lrow + r][col] = acc[r];
  }
  __syncthreads();

  // phase 2: per (edge, head) score + scatter
  for (int it = tid; it < 512; it += 256){
    int j = it >> 3, hh = it & 7;
    if (e0 + j >= E) continue;
    int sj = s_src[j], dj = s_dst[j];
    const f4* kp = (const f4*)(Kf + (size_t)sj * DM + hh * DH);
    const f4* qp = (const f4*)(Qf + (size_t)dj * DM + hh * DH);
    float dot = 0.f;
#pragma unroll
    for (int q = 0; q < 4; ++q){
      f4 kv = kp[q], qv = qp[q];
      const float* eh = &Eh[j][hh * DH + q * 4];
      dot += kv[0]*qv[0]*eh[0] + kv[1]*qv[1]*eh[1] + kv[2]*qv[2]*eh[2] + kv[3]*qv[3]*eh[3];
    }
    dot = fminf(5.f, fmaxf(-5.f, dot * 0.25f));
    float s = __expf(dot);
    atomicAdd(zf + (size_t)dj * NH + hh, s);
    const f4* vp = (const f4*)(Vf + (size_t)sj * DM + hh * DH);
    float* wp = wV + (size_t)dj * DM + hh * DH;
#pragma unroll
    for (int q = 0; q < 4; ++q){
      f4 vv = vp[q];
      atomicAdd(wp + q * 4 + 0, s * vv[0]);
      atomicAdd(wp + q * 4 + 1, s * vv[1]);
      atomicAdd(wp + q * 4 + 2, s * vv[2]);
      atomicAdd(wp + q * 4 + 3, s * vv[3]);
    }
  }
}

// ---------------- K3: h2 = h + (wV/z) @ Wo + bo ----------------
__global__ __launch_bounds__(256) void k_attnout(const float* __restrict__ wV,
    const float* __restrict__ zf, const float* __restrict__ h,
    const __bf16* __restrict__ WoT, const float* __restrict__ bo,
    float* __restrict__ h2, int N)
{
  int lane = threadIdx.x & 63;
  int r0 = (blockIdx.x * 4 + (threadIdx.x >> 6)) * 16;
  if (r0 + 16 > N) return;
  int arow = r0 + (lane & 15);
  int kof = (lane >> 4) << 3;
  bf8 a[4];
#pragma unroll
  for (int kt = 0; kt < 4; ++kt){
    int kb = kt * 32 + kof;
    float invz = 1.f / (zf[(size_t)arow * NH + (kb >> 4)] + 1e-6f);
    const f4* p = (const f4*)(wV + (size_t)arow * DM + kb);
    f4 u = p[0], v = p[1];
    bf8 r;
    r[0]=(__bf16)(u[0]*invz); r[1]=(__bf16)(u[1]*invz); r[2]=(__bf16)(u[2]*invz); r[3]=(__bf16)(u[3]*invz);
    r[4]=(__bf16)(v[0]*invz); r[5]=(__bf16)(v[1]*invz); r[6]=(__bf16)(v[2]*invz); r[7]=(__bf16)(v[3]*invz);
    a[kt] = r;
  }
  int crow = r0 + ((lane >> 4) << 2);
  int ccol = lane & 15;
#pragma unroll
  for (int nt = 0; nt < 8; ++nt){
    f4 acc = {0.f, 0.f, 0.f, 0.f};
#pragma unroll
    for (int kt = 0; kt < 4; ++kt)
      acc = mfma16(a[kt], bfragT(WoT + (size_t)(nt * 16) * DM + kt * 32, DM, lane), acc);
    int col = nt * 16 + ccol;
    float bb = bo[col];
#pragma unroll
    for (int r = 0; r < 4; ++r){
      size_t idx = (size_t)(crow + r) * DM + col;
      h2[idx] = h[idx] + acc[r] + bb;
    }
  }
}

// ---------------- BN stats / coef / apply ----------------
__global__ __launch_bounds__(256) void k_bnstats(const float* __restrict__ x,
    float* __restrict__ s1, float* __restrict__ s2, int N)
{
  __shared__ float p1[256], p2[256];
  int c = threadIdx.x & 127, g = threadIdx.x >> 7;
  float a1 = 0.f, a2 = 0.f;
  for (int r = blockIdx.x * 2 + g; r < N; r += gridDim.x * 2){
    float v = x[(size_t)r * DM + c];
    a1 += v; a2 += v * v;
  }
  p1[threadIdx.x] = a1; p2[threadIdx.x] = a2;
  __syncthreads();
  if (g == 0){
    atomicAdd(&s1[c], p1[threadIdx.x] + p1[threadIdx.x + 128]);
    atomicAdd(&s2[c], p2[threadIdx.x] + p2[threadIdx.x + 128]);
  }
}

__global__ void k_bncoef(const float* __restrict__ s1, const float* __restrict__ s2,
    const float* __restrict__ gam, const float* __restrict__ bet,
    float* __restrict__ cs, float* __restrict__ cb, int N)
{
  int c = threadIdx.x;
  if (c >= DM) return;
  float mean = s1[c] / (float)N;
  float var  = s2[c] / (float)N - mean * mean;
  float rs   = rsqrtf(var + 1e-5f);
  float sc   = gam[c] * rs;
  cs[c] = sc;
  cb[c] = bet[c] - mean * sc;
}

__global__ void k_bnapply(float* __restrict__ t, const float* __restrict__ cs,
    const float* __restrict__ cb, long long total4)
{
  long long i = (long long)blockIdx.x * blockDim.x + threadIdx.x;
  if (i >= total4) return;
  f4* p = (f4*)t + i;
  f4 v = *p;
  int c = (int)((i * 4) & (DM - 1));
  v[0] = v[0] * cs[c]     + cb[c];
  v[1] = v[1] * cs[c + 1] + cb[c + 1];
  v[2] = v[2] * cs[c + 2] + cb[c + 2];
  v[3] = v[3] * cs[c + 3] + cb[c + 3];
  *p = v;
}

// ---------------- K6: FFN fused (x=BN1(h2); t = x + relu(x@W1+b1)@W2 + b2) ----------------
__global__ __launch_bounds__(256) void k_ffn(const float* __restrict__ h2,
    const float* __restrict__ c1s, const float* __restrict__ c1b,
    const __bf16* __restrict__ W1T, const float* __restrict__ b1,
    const __bf16* __restrict__ W2T, const float* __restrict__ b2,
    float* __restrict__ t, int N)
{
  __shared__ __bf16 hid[4][16][256];   // 32 KiB
  int lane = threadIdx.x & 63, wave = threadIdx.x >> 6;
  int r0 = (blockIdx.x * 4 + wave) * 16;
  bool active = (r0 + 16 <= N);
  int r0c = active ? r0 : 0;

  int arow = r0c + (lane & 15);
  int kof = (lane >> 4) << 3;
  bf8 a[4];
#pragma unroll
  for (int kt = 0; kt < 4; ++kt){
    int kb = kt * 32 + kof;
    const f4* p  = (const f4*)(h2 + (size_t)arow * DM + kb);
    const f4* ps = (const f4*)(c1s + kb);
    const f4* pb = (const f4*)(c1b + kb);
    f4 u = p[0], v = p[1], s0 = ps[0], s1v = ps[1], b0 = pb[0], b1v = pb[1];
    bf8 r;
    r[0]=(__bf16)(u[0]*s0[0]+b0[0]); r[1]=(__bf16)(u[1]*s0[1]+b0[1]);
    r[2]=(__bf16)(u[2]*s0[2]+b0[2]); r[3]=(__bf16)(u[3]*s0[3]+b0[3]);
    r[4]=(__bf16)(v[0]*s1v[0]+b1v[0]); r[5]=(__bf16)(v[1]*s1v[1]+b1v[1]);
    r[6]=(__bf16)(v[2]*s1v[2]+b1v[2]); r[7]=(__bf16)(v[3]*s1v[3]+b1v[3]);
    a[kt] = r;
  }
  int lr = (lane >> 4) << 2;
  int ccol = lane & 15;
  // GEMM1: 16x256, relu -> LDS (bf16)
#pragma unroll
  for (int nt = 0; nt < 16; ++nt){
    f4 acc = {0.f, 0.f, 0.f, 0.f};
#pragma unroll
    for (int kt = 0; kt < 4; ++kt)
      acc = mfma16(a[kt], bfragT(W1T + (size_t)(nt * 16) * DM + kt * 32, DM, lane), acc);
    int col = nt * 16 + ccol;
    float bb = b1[col];
#pragma unroll
    for (int r = 0; r < 4; ++r)
      hid[wave][lr + r][col] = (__bf16)fmaxf(acc[r] + bb, 0.f);
  }
  __syncthreads();
  // GEMM2: 16x128, K=256
  f4 acc2[8];
#pragma unroll
  for (int nt = 0; nt < 8; ++nt){ acc2[nt][0]=0.f; acc2[nt][1]=0.f; acc2[nt][2]=0.f; acc2[nt][3]=0.f; }
#pragma unroll
  for (int kt = 0; kt < 8; ++kt){
    bf8 a2 = *(const bf8*)&hid[wave][lane & 15][kt * 32 + kof];
#pragma unroll
    for (int nt = 0; nt < 8; ++nt)
      acc2[nt] = mfma16(a2, bfragT(W2T + (size_t)(nt * 16) * 256 + kt * 32, 256, lane), acc2[nt]);
  }
  if (!active) return;
  int crow = r0 + lr;
#pragma unroll
  for (int nt = 0; nt < 8; ++nt){
    int col = nt * 16 + ccol;
    float bb = b2[col], sc = c1s[col], sb = c1b[col];
#pragma unroll
    for (int r = 0; r < 4; ++r){
      size_t idx = (size_t)(crow + r) * DM + col;
      float xres = h2[idx] * sc + sb;
      t[idx] = acc2[nt][r] + bb + xres;
    }
  }
}

// ---------------- host ----------------
extern "C" void kernel_launch(void* const* d_in, const int* in_sizes, int n_in,
                              void* d_out, int out_size, void* d_ws, size_t ws_size,
                              hipStream_t stream)
{
  const float* h    = (const float*)d_in[0];
  const float* e    = (const float*)d_in[2];
  const float* Wq   = (const float*)d_in[3];
  const float* Wk   = (const float*)d_in[4];
  const float* We   = (const float*)d_in[5];
  const float* Wv   = (const float*)d_in[6];
  const float* Wo   = (const float*)d_in[7];
  const float* bo   = (const float*)d_in[8];
  const float* bn1g = (const float*)d_in[9];
  const float* bn1b = (const float*)d_in[10];
  const float* bn2g = (const float*)d_in[11];
  const float* bn2b = (const float*)d_in[12];
  const float* W1   = (const float*)d_in[13];
  const float* b1   = (const float*)d_in[14];
  const float* W2   = (const float*)d_in[15];
  const float* b2   = (const float*)d_in[16];
  const int*   src  = (const int*)d_in[17];
  const int*   dst  = (const int*)d_in[18];

  int N = in_sizes[0] / DM;
  int E = in_sizes[2] / DM;
  float* out = (float*)d_out;

  char* ws = (char*)d_ws;
  size_t off = 0;
  auto alloc = [&](size_t bytes) -> char* {
    char* r = ws + off;
    off += (bytes + 255) & ~(size_t)255;
    return r;
  };
  float* Qf  = (float*)alloc((size_t)N * DM * 4);
  float* Kf  = (float*)alloc((size_t)N * DM * 4);
  float* Vf  = (float*)alloc((size_t)N * DM * 4);
  float* wV  = (float*)alloc((size_t)N * DM * 4);
  float* zf  = (float*)alloc((size_t)N * NH * 4);
  float* h2  = (float*)alloc((size_t)N * DM * 4);
  float* stats = (float*)alloc(1024 * 4);   // s1a s2a s1b s2b c1s c1b c2s c2b
  float* s1a = stats, *s2a = stats + 128, *s1b = stats + 256, *s2b = stats + 384;
  float* c1s = stats + 512, *c1b = stats + 640, *c2s = stats + 768, *c2b = stats + 896;
  __bf16* WqT = (__bf16*)alloc(16384 * 2);
  __bf16* WkT = (__bf16*)alloc(16384 * 2);
  __bf16* WvT = (__bf16*)alloc(16384 * 2);
  __bf16* WeT = (__bf16*)alloc(16384 * 2);
  __bf16* WoT = (__bf16*)alloc(16384 * 2);
  __bf16* W1T = (__bf16*)alloc(32768 * 2);
  __bf16* W2T = (__bf16*)alloc(32768 * 2);

  hipMemsetAsync(wV, 0, (size_t)N * DM * 4, stream);
  hipMemsetAsync(zf, 0, (size_t)N * NH * 4, stream);
  hipMemsetAsync(stats, 0, 512 * 4, stream);

  k_transpose<<<64, 256, 0, stream>>>(Wq, WqT, DM, DM);
  k_transpose<<<64, 256, 0, stream>>>(Wk, WkT, DM, DM);
  k_transpose<<<64, 256, 0, stream>>>(Wv, WvT, DM, DM);
  k_transpose<<<64, 256, 0, stream>>>(We, WeT, DM, DM);
  k_transpose<<<64, 256, 0, stream>>>(Wo, WoT, DM, DM);
  k_transpose<<<128, 256, 0, stream>>>(W1, W1T, DM, 256);
  k_transpose<<<128, 256, 0, stream>>>(W2, W2T, 256, DM);

  int rowblocks = (N / 16 + 3) / 4;
  k_qkv<<<rowblocks, 256, 0, stream>>>(h, WqT, WkT, WvT, Qf, Kf, Vf, N);
  k_edge<<<(E + 63) / 64, 256, 0, stream>>>(e, WeT, Qf, Kf, Vf, src, dst, wV, zf, E);
  k_attnout<<<rowblocks, 256, 0, stream>>>(wV, zf, h, WoT, bo, h2, N);
  k_bnstats<<<256, 256, 0, stream>>>(h2, s1a, s2a, N);
  k_bncoef<<<1, 128, 0, stream>>>(s1a, s2a, bn1g, bn1b, c1s, c1b, N);
  k_ffn<<<rowblocks, 256, 0, stream>>>(h2, c1s, c1b, W1T, b1, W2T, b2, out, N);
  k_bnstats<<<256, 256, 0, stream>>>(out, s1b, s2b, N);
  k_bncoef<<<1, 128, 0, stream>>>(s1b, s2b, bn2g, bn2b, c2s, c2b, N);
  long long total4 = (long long)N * DM / 4;
  k_bnapply<<<(int)((total4 + 255) / 256), 256, 0, stream>>>(out, c2s, c2b, total4);
}

// Round 2
// 832.121 us; speedup vs baseline: 7.4105x; 7.4105x over previous
//
#include <hip/hip_runtime.h>

#define DM 128
#define NH 8
#define DH 16

typedef __bf16 bf8 __attribute__((ext_vector_type(8)));
typedef float  f4  __attribute__((ext_vector_type(4)));

__device__ __forceinline__ f4 mfma16(bf8 a, bf8 b, f4 c){
  return __builtin_amdgcn_mfma_f32_16x16x32_bf16(a, b, c, 0, 0, 0);
}

// convert 8 contiguous fp32 -> bf16x8 fragment
__device__ __forceinline__ bf8 cvt8(const float* __restrict__ p){
  f4 u = *(const f4*)p;
  f4 v = *(const f4*)(p + 4);
  bf8 r;
  r[0]=(__bf16)u[0]; r[1]=(__bf16)u[1]; r[2]=(__bf16)u[2]; r[3]=(__bf16)u[3];
  r[4]=(__bf16)v[0]; r[5]=(__bf16)v[1]; r[6]=(__bf16)v[2]; r[7]=(__bf16)v[3];
  return r;
}

// B fragment from pre-transposed bf16 weight WT[out][k]; ptr must be at (col0,k0)
__device__ __forceinline__ bf8 bfragT(const __bf16* __restrict__ WT, int ldk, int lane){
  const __bf16* p = WT + (size_t)(lane & 15) * ldk + ((lane >> 4) << 3);
  return *(const bf8*)p;
}

// ---------------- weight prep: W[K][M] (fp32) -> WT[M][K] (bf16) ----------------
__global__ void k_transpose(const float* __restrict__ W, __bf16* __restrict__ WT, int K, int M){
  int idx = blockIdx.x * 256 + threadIdx.x;
  if (idx >= K * M) return;
  int m = idx / K, k = idx - m * K;
  WT[idx] = (__bf16)W[(size_t)k * M + m];
}

// ---------------- CSR build ----------------
__global__ void k_hist(const int* __restrict__ dst, int* __restrict__ deg, int E){
  int i = blockIdx.x * 256 + threadIdx.x;
  if (i < E) atomicAdd(&deg[dst[i]], 1);
}

__global__ __launch_bounds__(1024) void k_scan(const int* __restrict__ deg,
    int* __restrict__ off, int* __restrict__ cursor, int N)
{
  __shared__ int part[1024];
  int t = threadIdx.x;
  int C = (N + 1023) >> 10;
  int base = t * C;
  int sum = 0;
  for (int i = 0; i < C; ++i){ int idx = base + i; if (idx < N) sum += deg[idx]; }
  part[t] = sum;
  __syncthreads();
  for (int d = 1; d < 1024; d <<= 1){
    int add = (t >= d) ? part[t - d] : 0;
    __syncthreads();
    part[t] += add;
    __syncthreads();
  }
  int run = (t == 0) ? 0 : part[t - 1];
  for (int i = 0; i < C; ++i){
    int idx = base + i;
    if (idx < N){ off[idx] = run; cursor[idx] = run; run += deg[idx]; }
  }
}

// ---------------- K1: Q,K,V = h @ Wq/Wk/Wv ----------------
__global__ __launch_bounds__(256) void k_qkv(const float* __restrict__ h,
    const __bf16* __restrict__ WqT, const __bf16* __restrict__ WkT, const __bf16* __restrict__ WvT,
    float* __restrict__ Q, float* __restrict__ K, float* __restrict__ V, int N)
{
  int lane = threadIdx.x & 63;
  int r0 = (blockIdx.x * 4 + (threadIdx.x >> 6)) * 16;
  if (r0 + 16 > N) return;
  bf8 a[4];
  int arow = r0 + (lane & 15);
  int koff = (lane >> 4) << 3;
#pragma unroll
  for (int kt = 0; kt < 4; ++kt)
    a[kt] = cvt8(h + (size_t)arow * DM + kt * 32 + koff);

  const __bf16* Ws[3] = {WqT, WkT, WvT};
  float* Os[3] = {Q, K, V};
  int crow = r0 + ((lane >> 4) << 2);
  int ccol = lane & 15;
#pragma unroll
  for (int o = 0; o < 3; ++o){
#pragma unroll
    for (int nt = 0; nt < 8; ++nt){
      f4 acc = {0.f, 0.f, 0.f, 0.f};
#pragma unroll
      for (int kt = 0; kt < 4; ++kt)
        acc = mfma16(a[kt], bfragT(Ws[o] + (size_t)(nt * 16) * DM + kt * 32, DM, lane), acc);
      float* outp = Os[o] + (size_t)crow * DM + nt * 16 + ccol;
      outp[0] = acc[0]; outp[DM] = acc[1]; outp[2 * DM] = acc[2]; outp[3 * DM] = acc[3];
    }
  }
}

// ---------------- K2: fused Eh GEMM + edge scoring + CSR slot write ----------------
__global__ __launch_bounds__(256) void k_edge(const float* __restrict__ e,
    const __bf16* __restrict__ WeT,
    const float* __restrict__ Qf, const float* __restrict__ Kf,
    const int* __restrict__ src, const int* __restrict__ dst,
    int* __restrict__ cursor, int* __restrict__ sSrc, float* __restrict__ sS, int E)
{
  __shared__ float Eh[64][132];     // +4 pad: breaks 32-way bank conflict on head-slice reads
  __shared__ int s_src[64], s_dst[64], s_slot[64];
  int tid = threadIdx.x, lane = tid & 63, wave = tid >> 6;
  int e0 = blockIdx.x * 64;
  if (tid < 64){
    int ei = e0 + tid;
    bool v = ei < E;
    s_src[tid] = v ? src[ei] : 0;
    s_dst[tid] = v ? dst[ei] : 0;
  }
  // phase 1: Eh tile = e[e0:e0+64] @ We  (each wave does 16 rows)
  int er = e0 + wave * 16 + (lane & 15);
  if (er >= E) er = E - 1;
  int koff = (lane >> 4) << 3;
  bf8 a[4];
#pragma unroll
  for (int kt = 0; kt < 4; ++kt)
    a[kt] = cvt8(e + (size_t)er * DM + kt * 32 + koff);
  int lrow = wave * 16 + ((lane >> 4) << 2);
  int ccol = lane & 15;
#pragma unroll
  for (int nt = 0; nt < 8; ++nt){
    f4 acc = {0.f, 0.f, 0.f, 0.f};
#pragma unroll
    for (int kt = 0; kt < 4; ++kt)
      acc = mfma16(a[kt], bfragT(WeT + (size_t)(nt * 16) * DM + kt * 32, DM, lane), acc);
    int col = nt * 16 + ccol;
#pragma unroll
    for (int r = 0; r < 4; ++r) Eh[lrow + r][col] = acc[r];
  }
  __syncthreads();

  // phase 2a: CSR slot allocation (one int atomic per edge)
  if (tid < 64 && e0 + tid < E){
    int slot = atomicAdd(&cursor[s_dst[tid]], 1);
    s_slot[tid] = slot;
    sSrc[slot] = s_src[tid];
  }
  __syncthreads();

  // phase 2b: per (edge, head) score -> CSR slot
  for (int it = tid; it < 512; it += 256){
    int j = it >> 3, hh = it & 7;
    if (e0 + j >= E) continue;
    int sj = s_src[j], dj = s_dst[j];
    const f4* kp = (const f4*)(Kf + (size_t)sj * DM + hh * DH);
    const f4* qp = (const f4*)(Qf + (size_t)dj * DM + hh * DH);
    float dot = 0.f;
#pragma unroll
    for (int q = 0; q < 4; ++q){
      f4 kv = kp[q], qv = qp[q];
      const float* eh = &Eh[j][hh * DH + q * 4];
      dot += kv[0]*qv[0]*eh[0] + kv[1]*qv[1]*eh[1] + kv[2]*qv[2]*eh[2] + kv[3]*qv[3]*eh[3];
    }
    dot = fminf(5.f, fmaxf(-5.f, dot * 0.25f));
    sS[(size_t)s_slot[j] * NH + hh] = __expf(dot);
  }
}

// ---------------- K2c: per-node gather reduction -> normalized h_attn ----------------
__global__ __launch_bounds__(256) void k_gather(const int* __restrict__ off,
    const int* __restrict__ deg, const int* __restrict__ sSrc, const float* __restrict__ sS,
    const float* __restrict__ Vf, float* __restrict__ hattn, int N)
{
  int node = blockIdx.x * 4 + (threadIdx.x >> 6);
  if (node >= N) return;
  int lane = threadIdx.x & 63;
  int start = off[node], d = deg[node];
  int h0 = lane >> 4;            // head of dim `lane`
  float a0 = 0.f, a1 = 0.f, z0 = 0.f, z1 = 0.f;
  for (int i = 0; i < d; ++i){
    int eid = start + i;
    int sj = sSrc[eid];
    float s0 = sS[(size_t)eid * NH + h0];
    float s1 = sS[(size_t)eid * NH + 4 + h0];
    float v0 = Vf[(size_t)sj * DM + lane];
    float v1 = Vf[(size_t)sj * DM + 64 + lane];
    a0 += s0 * v0; a1 += s1 * v1;
    z0 += s0;      z1 += s1;
  }
  hattn[(size_t)node * DM + lane]      = a0 / (z0 + 1e-6f);
  hattn[(size_t)node * DM + 64 + lane] = a1 / (z1 + 1e-6f);
}

// ---------------- K3: h2 = h + h_attn @ Wo + bo ----------------
__global__ __launch_bounds__(256) void k_attnout(const float* __restrict__ hattn,
    const float* __restrict__ h,
    const __bf16* __restrict__ WoT, const float* __restrict__ bo,
    float* __restrict__ h2, int N)
{
  int lane = threadIdx.x & 63;
  int r0 = (blockIdx.x * 4 + (threadIdx.x >> 6)) * 16;
  if (r0 + 16 > N) return;
  int arow = r0 + (lane & 15);
  int kof = (lane >> 4) << 3;
  bf8 a[4];
#pragma unroll
  for (int kt = 0; kt < 4; ++kt)
    a[kt] = cvt8(hattn + (size_t)arow * DM + kt * 32 + kof);
  int crow = r0 + ((lane >> 4) << 2);
  int ccol = lane & 15;
#pragma unroll
  for (int nt = 0; nt < 8; ++nt){
    f4 acc = {0.f, 0.f, 0.f, 0.f};
#pragma unroll
    for (int kt = 0; kt < 4; ++kt)
      acc = mfma16(a[kt], bfragT(WoT + (size_t)(nt * 16) * DM + kt * 32, DM, lane), acc);
    int col = nt * 16 + ccol;
    float bb = bo[col];
#pragma unroll
    for (int r = 0; r < 4; ++r){
      size_t idx = (size_t)(crow + r) * DM + col;
      h2[idx] = h[idx] + acc[r] + bb;
    }
  }
}

// ---------------- BN stats / coef / apply ----------------
__global__ __launch_bounds__(256) void k_bnstats(const float* __restrict__ x,
    float* __restrict__ s1, float* __restrict__ s2, int N)
{
  __shared__ float p1[256], p2[256];
  int c = threadIdx.x & 127, g = threadIdx.x >> 7;
  float a1 = 0.f, a2 = 0.f;
  for (int r = blockIdx.x * 2 + g; r < N; r += gridDim.x * 2){
    float v = x[(size_t)r * DM + c];
    a1 += v; a2 += v * v;
  }
  p1[threadIdx.x] = a1; p2[threadIdx.x] = a2;
  __syncthreads();
  if (g == 0){
    atomicAdd(&s1[c], p1[threadIdx.x] + p1[threadIdx.x + 128]);
    atomicAdd(&s2[c], p2[threadIdx.x] + p2[threadIdx.x + 128]);
  }
}

__global__ void k_bncoef(const float* __restrict__ s1, const float* __restrict__ s2,
    const float* __restrict__ gam, const float* __restrict__ bet,
    float* __restrict__ cs, float* __restrict__ cb, int N)
{
  int c = threadIdx.x;
  if (c >= DM) return;
  float mean = s1[c] / (float)N;
  float var  = s2[c] / (float)N - mean * mean;
  float rs   = rsqrtf(var + 1e-5f);
  float sc   = gam[c] * rs;
  cs[c] = sc;
  cb[c] = bet[c] - mean * sc;
}

__global__ void k_bnapply(float* __restrict__ t, const float* __restrict__ cs,
    const float* __restrict__ cb, long long total4)
{
  long long i = (long long)blockIdx.x * blockDim.x + threadIdx.x;
  if (i >= total4) return;
  f4* p = (f4*)t + i;
  f4 v = *p;
  int c = (int)((i * 4) & (DM - 1));
  v[0] = v[0] * cs[c]     + cb[c];
  v[1] = v[1] * cs[c + 1] + cb[c + 1];
  v[2] = v[2] * cs[c + 2] + cb[c + 2];
  v[3] = v[3] * cs[c + 3] + cb[c + 3];
  *p = v;
}

// ---------------- K6: FFN fused (x=BN1(h2); t = x + relu(x@W1+b1)@W2 + b2) ----------------
__global__ __launch_bounds__(256) void k_ffn(const float* __restrict__ h2,
    const float* __restrict__ c1s, const float* __restrict__ c1b,
    const __bf16* __restrict__ W1T, const float* __restrict__ b1,
    const __bf16* __restrict__ W2T, const float* __restrict__ b2,
    float* __restrict__ t, int N)
{
  __shared__ __bf16 hid[4][16][256];   // 32 KiB
  int lane = threadIdx.x & 63, wave = threadIdx.x >> 6;
  int r0 = (blockIdx.x * 4 + wave) * 16;
  bool active = (r0 + 16 <= N);
  int r0c = active ? r0 : 0;

  int arow = r0c + (lane & 15);
  int kof = (lane >> 4) << 3;
  bf8 a[4];
#pragma unroll
  for (int kt = 0; kt < 4; ++kt){
    int kb = kt * 32 + kof;
    const f4* p  = (const f4*)(h2 + (size_t)arow * DM + kb);
    const f4* ps = (const f4*)(c1s + kb);
    const f4* pb = (const f4*)(c1b + kb);
    f4 u = p[0], v = p[1], s0 = ps[0], s1v = ps[1], b0 = pb[0], b1v = pb[1];
    bf8 r;
    r[0]=(__bf16)(u[0]*s0[0]+b0[0]); r[1]=(__bf16)(u[1]*s0[1]+b0[1]);
    r[2]=(__bf16)(u[2]*s0[2]+b0[2]); r[3]=(__bf16)(u[3]*s0[3]+b0[3]);
    r[4]=(__bf16)(v[0]*s1v[0]+b1v[0]); r[5]=(__bf16)(v[1]*s1v[1]+b1v[1]);
    r[6]=(__bf16)(v[2]*s1v[2]+b1v[2]); r[7]=(__bf16)(v[3]*s1v[3]+b1v[3]);
    a[kt] = r;
  }
  int lr = (lane >> 4) << 2;
  int ccol = lane & 15;
  // GEMM1: 16x256, relu -> LDS (bf16)
#pragma unroll
  for (int nt = 0; nt < 16; ++nt){
    f4 acc = {0.f, 0.f, 0.f, 0.f};
#pragma unroll
    for (int kt = 0; kt < 4; ++kt)
      acc = mfma16(a[kt], bfragT(W1T + (size_t)(nt * 16) * DM + kt * 32, DM, lane), acc);
    int col = nt * 16 + ccol;
    float bb = b1[col];
#pragma unroll
    for (int r = 0; r < 4; ++r)
      hid[wave][lr + r][col] = (__bf16)fmaxf(acc[r] + bb, 0.f);
  }
  __syncthreads();
  // GEMM2: 16x128, K=256
  f4 acc2[8];
#pragma unroll
  for (int nt = 0; nt < 8; ++nt){ acc2[nt][0]=0.f; acc2[nt][1]=0.f; acc2[nt][2]=0.f; acc2[nt][3]=0.f; }
#pragma unroll
  for (int kt = 0; kt < 8; ++kt){
    bf8 a2 = *(const bf8*)&hid[wave][lane & 15][kt * 32 + kof];
#pragma unroll
    for (int nt = 0; nt < 8; ++nt)
      acc2[nt] = mfma16(a2, bfragT(W2T + (size_t)(nt * 16) * 256 + kt * 32, 256, lane), acc2[nt]);
  }
  if (!active) return;
  int crow = r0 + lr;
#pragma unroll
  for (int nt = 0; nt < 8; ++nt){
    int col = nt * 16 + ccol;
    float bb = b2[col], sc = c1s[col], sb = c1b[col];
#pragma unroll
    for (int r = 0; r < 4; ++r){
      size_t idx = (size_t)(crow + r) * DM + col;
      float xres = h2[idx] * sc + sb;
      t[idx] = acc2[nt][r] + bb + xres;
    }
  }
}

// ---------------- host ----------------
extern "C" void kernel_launch(void* const* d_in, const int* in_sizes, int n_in,
                              void* d_out, int out_size, void* d_ws, size_t ws_size,
                              hipStream_t stream)
{
  const float* h    = (const float*)d_in[0];
  const float* e    = (const float*)d_in[2];
  const float* Wq   = (const float*)d_in[3];
  const float* Wk   = (const float*)d_in[4];
  const float* We   = (const float*)d_in[5];
  const float* Wv   = (const float*)d_in[6];
  const float* Wo   = (const float*)d_in[7];
  const float* bo   = (const float*)d_in[8];
  const float* bn1g = (const float*)d_in[9];
  const float* bn1b = (const float*)d_in[10];
  const float* bn2g = (const float*)d_in[11];
  const float* bn2b = (const float*)d_in[12];
  const float* W1   = (const float*)d_in[13];
  const float* b1   = (const float*)d_in[14];
  const float* W2   = (const float*)d_in[15];
  const float* b2   = (const float*)d_in[16];
  const int*   src  = (const int*)d_in[17];
  const int*   dst  = (const int*)d_in[18];

  int N = in_sizes[0] / DM;
  int E = in_sizes[2] / DM;
  float* out = (float*)d_out;

  char* ws = (char*)d_ws;
  size_t off_b = 0;
  auto alloc = [&](size_t bytes) -> char* {
    char* r = ws + off_b;
    off_b += (bytes + 255) & ~(size_t)255;
    return r;
  };
  float* Qf    = (float*)alloc((size_t)N * DM * 4);
  float* Kf    = (float*)alloc((size_t)N * DM * 4);
  float* Vf    = (float*)alloc((size_t)N * DM * 4);
  float* hattn = (float*)alloc((size_t)N * DM * 4);
  float* h2    = (float*)alloc((size_t)N * DM * 4);
  int*   deg    = (int*)alloc((size_t)N * 4);
  int*   offs   = (int*)alloc((size_t)N * 4);
  int*   cursor = (int*)alloc((size_t)N * 4);
  int*   sSrc   = (int*)alloc((size_t)E * 4);
  float* sS     = (float*)alloc((size_t)E * NH * 4);
  float* stats = (float*)alloc(1024 * 4);   // s1a s2a s1b s2b c1s c1b c2s c2b
  float* s1a = stats, *s2a = stats + 128, *s1b = stats + 256, *s2b = stats + 384;
  float* c1s = stats + 512, *c1b = stats + 640, *c2s = stats + 768, *c2b = stats + 896;
  __bf16* WqT = (__bf16*)alloc(16384 * 2);
  __bf16* WkT = (__bf16*)alloc(16384 * 2);
  __bf16* WvT = (__bf16*)alloc(16384 * 2);
  __bf16* WeT = (__bf16*)alloc(16384 * 2);
  __bf16* WoT = (__bf16*)alloc(16384 * 2);
  __bf16* W1T = (__bf16*)alloc(32768 * 2);
  __bf16* W2T = (__bf16*)alloc(32768 * 2);

  hipMemsetAsync(deg, 0, (size_t)N * 4, stream);
  hipMemsetAsync(stats, 0, 512 * 4, stream);

  k_transpose<<<64, 256, 0, stream>>>(Wq, WqT, DM, DM);
  k_transpose<<<64, 256, 0, stream>>>(Wk, WkT, DM, DM);
  k_transpose<<<64, 256, 0, stream>>>(Wv, WvT, DM, DM);
  k_transpose<<<64, 256, 0, stream>>>(We, WeT, DM, DM);
  k_transpose<<<64, 256, 0, stream>>>(Wo, WoT, DM, DM);
  k_transpose<<<128, 256, 0, stream>>>(W1, W1T, DM, 256);
  k_transpose<<<128, 256, 0, stream>>>(W2, W2T, 256, DM);

  k_hist<<<(E + 255) / 256, 256, 0, stream>>>(dst, deg, E);
  k_scan<<<1, 1024, 0, stream>>>(deg, offs, cursor, N);

  int rowblocks = (N / 16 + 3) / 4;
  k_qkv<<<rowblocks, 256, 0, stream>>>(h, WqT, WkT, WvT, Qf, Kf, Vf, N);
  k_edge<<<(E + 63) / 64, 256, 0, stream>>>(e, WeT, Qf, Kf, src, dst, cursor, sSrc, sS, E);
  k_gather<<<(N + 3) / 4, 256, 0, stream>>>(offs, deg, sSrc, sS, Vf, hattn, N);
  k_attnout<<<rowblocks, 256, 0, stream>>>(hattn, h, WoT, bo, h2, N);
  k_bnstats<<<256, 256, 0, stream>>>(h2, s1a, s2a, N);
  k_bncoef<<<1, 128, 0, stream>>>(s1a, s2a, bn1g, bn1b, c1s, c1b, N);
  k_ffn<<<rowblocks, 256, 0, stream>>>(h2, c1s, c1b, W1T, b1, W2T, b2, out, N);
  k_bnstats<<<256, 256, 0, stream>>>(out, s1b, s2b, N);
  k_bncoef<<<1, 128, 0, stream>>>(s1b, s2b, bn2g, bn2b, c2s, c2b, N);
  long long total4 = (long long)N * DM / 4;
  k_bnapply<<<(int)((total4 + 255) / 256), 256, 0, stream>>>(out, c2s, c2b, total4);
}